// Round 5
// baseline (76.436 us; speedup 1.0000x reference)
//
#include <hip/hip_runtime.h>
#include <hip/hip_bf16.h>
#include <cstdint>
#include <cstddef>

#define NS 2560
#define NQ 8192
#define NC 512
#define DD 1600

typedef __bf16 bf16_t;
typedef __bf16 bf16x4 __attribute__((ext_vector_type(4)));
typedef __bf16 bf16x8 __attribute__((ext_vector_type(8)));
typedef float f32x4 __attribute__((ext_vector_type(4)));

// ---------------------------------------------------------------------------
// Kernel 1: class-mean prototypes (bf16) + ||p||^2 (fp32). One block per class.
// ---------------------------------------------------------------------------
__global__ __launch_bounds__(256) void proto_kernel(
    const float* __restrict__ sup, const int* __restrict__ lab,
    bf16_t* __restrict__ protos, float* __restrict__ p2)
{
    const int m   = blockIdx.x;
    const int tid = threadIdx.x;
    __shared__ int   idxs[32];
    __shared__ int   cnt;
    __shared__ float wsum[4];
    if (tid == 0) cnt = 0;
    __syncthreads();
    for (int i = tid; i < NS; i += 256) {
        if (lab[i] == m) {
            int p = atomicAdd(&cnt, 1);
            if (p < 32) idxs[p] = i;
        }
    }
    __syncthreads();
    int n = cnt < 32 ? cnt : 32;
    if (tid == 0 && n > 1) {                       // deterministic order
        for (int a = 1; a < n; ++a) {
            int key = idxs[a]; int b = a - 1;
            while (b >= 0 && idxs[b] > key) { idxs[b+1] = idxs[b]; --b; }
            idxs[b+1] = key;
        }
    }
    __syncthreads();

    float acc[7];
    #pragma unroll
    for (int u = 0; u < 7; ++u) acc[u] = 0.f;
    for (int t = 0; t < n; ++t) {
        const float* src = sup + (size_t)idxs[t] * DD;
        #pragma unroll
        for (int u = 0; u < 7; ++u) {
            int j = tid + u * 256;
            if (j < DD) acc[u] += src[j];
        }
    }
    float inv = (n > 0) ? 1.f / (float)n : 0.f;
    float psq = 0.f;
    #pragma unroll
    for (int u = 0; u < 7; ++u) {
        int j = tid + u * 256;
        if (j < DD) {
            float p = acc[u] * inv;
            bf16_t pb = (bf16_t)p;
            protos[(size_t)m * DD + j] = pb;
            float pf = (float)pb;
            psq += pf * pf;
        }
    }
    #pragma unroll
    for (int o = 32; o > 0; o >>= 1) psq += __shfl_xor(psq, o);
    int lane = tid & 63, wid = tid >> 6;
    if (lane == 0) wsum[wid] = psq;
    __syncthreads();
    if (tid == 0) p2[m] = wsum[0] + wsum[1] + wsum[2] + wsum[3];
}

// ---------------------------------------------------------------------------
// Kernel 2 (fused, B-in-registers): 32 query rows x ALL 512 classes per
// block; K=1600 in 25 steps of BK=64. Wave w owns cols [w*64,w*64+64).
//   B: NO LDS. MFMA B-frag for lane (r,g) = 16 contiguous bytes of
//      protos[col=ni*16+r] at K-offset kk*32+g*8 -> one global_load_dwordx4
//      per frag, software-pipelined 1 tile ahead in two named reg sets.
//   A: shared 32x64 bf16 tile (fp32->bf16 reg-staged), dbuf 2x4 KB LDS,
//      XOR-swizzled; raw s_barrier + lgkmcnt(0) per iter (no vmcnt drain:
//      next B tile's 8 loads stay in flight across the barrier).
// Epilogue: logits = 2*dot - |p|^2, fused row log_softmax, store.
// ---------------------------------------------------------------------------
__device__ __forceinline__ void gemm_body(
    bf16x8 (&BC)[8], bf16x8 (&BN)[8], const char* ACUR, char* ANXT,
    int T, const char* bbase, const float* aptr, int aoff,
    int r, int g, f32x4 (&acc)[2][4])
{
    const int  Tn  = T + 1;
    const bool pre = (Tn < 25);

    // ---- issue next tile: fA FIRST (older -> cvt waits vmcnt(8)), then B ----
    float4 fA;
    if (pre) {
        fA = *(const float4*)(aptr + Tn * 64);
        #pragma unroll
        for (int ni = 0; ni < 4; ++ni)
            #pragma unroll
            for (int kk = 0; kk < 2; ++kk)
                BN[ni * 2 + kk] = *(const bf16x8*)(bbase
                    + ni * (16 * 2 * DD) + Tn * 128 + kk * 64);
    }
    __builtin_amdgcn_sched_barrier(0);

    // ---- A fragments from LDS (compiler inserts lgkmcnt waits) ----
    bf16x8 af[2][2];
    #pragma unroll
    for (int kk = 0; kk < 2; ++kk)
        #pragma unroll
        for (int mi = 0; mi < 2; ++mi)
            af[kk][mi] = *(const bf16x8*)(ACUR +
                ((((mi * 16 + r) * 128) + kk * 64 + g * 16) ^ ((r & 7) << 4)));

    // ---- 16 MFMA on current tile (compiler waits vmcnt for BC, 9 newer stay) ----
    #pragma unroll
    for (int kk = 0; kk < 2; ++kk)
        #pragma unroll
        for (int mi = 0; mi < 2; ++mi)
            #pragma unroll
            for (int ni = 0; ni < 4; ++ni)
                acc[mi][ni] = __builtin_amdgcn_mfma_f32_16x16x32_bf16(
                    af[kk][mi], BC[ni * 2 + kk], acc[mi][ni], 0, 0, 0);

    // ---- convert + ds_write A(T+1) into other buffer ----
    if (pre) {
        bf16x4 w;
        w[0] = (bf16_t)fA.x; w[1] = (bf16_t)fA.y;
        w[2] = (bf16_t)fA.z; w[3] = (bf16_t)fA.w;
        *(bf16x4*)(ANXT + aoff) = w;
    }
    asm volatile("s_waitcnt lgkmcnt(0)" ::: "memory");
    __builtin_amdgcn_sched_barrier(0);
    __builtin_amdgcn_s_barrier();          // raw: B loads stay in flight
    __builtin_amdgcn_sched_barrier(0);
}

__global__ __launch_bounds__(512, 2) void fused_kernel(
    const float* __restrict__ q, const bf16_t* __restrict__ protos,
    const float* __restrict__ p2, float* __restrict__ out)
{
    __shared__ char  Asm[2][4096];
    __shared__ float red[32 * 8];
    __shared__ float gmaxs[32];
    __shared__ float lses[32];

    const int tid  = threadIdx.x;
    const int lane = tid & 63;
    const int wid  = tid >> 6;        // wave = 64-col strip 0..7
    const int r    = lane & 15;
    const int g    = lane >> 4;
    const int m0   = blockIdx.x * 32;

    // B-fragment base: col-major lane mapping (col = wid*64 + ni*16 + r),
    // 16B at protos[col]*2*DD + T*128 + kk*64 + g*16
    const char* bbase = (const char*)protos + (size_t)(wid * 64 + r) * (2 * DD) + g * 16;

    float p2c[4];
    #pragma unroll
    for (int ni = 0; ni < 4; ++ni) p2c[ni] = p2[wid * 64 + ni * 16 + r];

    f32x4 acc[2][4];
    #pragma unroll
    for (int mi = 0; mi < 2; ++mi)
        #pragma unroll
        for (int ni = 0; ni < 4; ++ni)
            acc[mi][ni] = (f32x4){0.f, 0.f, 0.f, 0.f};

    const int arow = tid >> 4;        // 0..31
    const int acg  = tid & 15;        // 4-float column group
    const float* aptr = q + (size_t)(m0 + arow) * DD + acg * 4;
    const int    aoff = (arow * 128 + acg * 8) ^ ((arow & 7) << 4);

    bf16x8 b0[8], b1[8];

    // ---- prologue: fA(0) first, then B(0) frags, then A(0) write+barrier ----
    {
        float4 f = *(const float4*)(aptr);
        __builtin_amdgcn_sched_barrier(0);
        #pragma unroll
        for (int ni = 0; ni < 4; ++ni)
            #pragma unroll
            for (int kk = 0; kk < 2; ++kk)
                b0[ni * 2 + kk] = *(const bf16x8*)(bbase
                    + ni * (16 * 2 * DD) + kk * 64);
        __builtin_amdgcn_sched_barrier(0);
        bf16x4 w;
        w[0] = (bf16_t)f.x; w[1] = (bf16_t)f.y; w[2] = (bf16_t)f.z; w[3] = (bf16_t)f.w;
        *(bf16x4*)(&Asm[0][0] + aoff) = w;
        asm volatile("s_waitcnt lgkmcnt(0)" ::: "memory");
        __builtin_amdgcn_sched_barrier(0);
        __builtin_amdgcn_s_barrier();
        __builtin_amdgcn_sched_barrier(0);
    }

    // ---- 25 bodies, 2x unrolled with named reg sets (no runtime indexing) ----
    for (int tt = 0; tt < 24; tt += 2) {
        gemm_body(b0, b1, &Asm[0][0], &Asm[1][0], tt,     bbase, aptr, aoff, r, g, acc);
        gemm_body(b1, b0, &Asm[1][0], &Asm[0][0], tt + 1, bbase, aptr, aoff, r, g, acc);
    }
    gemm_body(b0, b1, &Asm[0][0], &Asm[1][0], 24, bbase, aptr, aoff, r, g, acc);

    // ---- logits = 2*dot - |p|^2 ----
    #pragma unroll
    for (int mi = 0; mi < 2; ++mi)
        #pragma unroll
        for (int ni = 0; ni < 4; ++ni)
            #pragma unroll
            for (int j = 0; j < 4; ++j)
                acc[mi][ni][j] = 2.f * acc[mi][ni][j] - p2c[ni];

    // ---- fused log_softmax over 512 cols ----
    float rmax[2][4];
    #pragma unroll
    for (int mi = 0; mi < 2; ++mi)
        #pragma unroll
        for (int j = 0; j < 4; ++j) {
            float m = acc[mi][0][j];
            #pragma unroll
            for (int ni = 1; ni < 4; ++ni) m = fmaxf(m, acc[mi][ni][j]);
            rmax[mi][j] = m;
        }
    #pragma unroll
    for (int o = 1; o < 16; o <<= 1)
        #pragma unroll
        for (int mi = 0; mi < 2; ++mi)
            #pragma unroll
            for (int j = 0; j < 4; ++j)
                rmax[mi][j] = fmaxf(rmax[mi][j], __shfl_xor(rmax[mi][j], o));
    if (r == 0) {
        #pragma unroll
        for (int mi = 0; mi < 2; ++mi)
            #pragma unroll
            for (int j = 0; j < 4; ++j)
                red[(mi * 16 + g * 4 + j) * 8 + wid] = rmax[mi][j];
    }
    __syncthreads();
    if (tid < 32) {
        float m = red[tid * 8];
        #pragma unroll
        for (int w = 1; w < 8; ++w) m = fmaxf(m, red[tid * 8 + w]);
        gmaxs[tid] = m;
    }
    __syncthreads();

    float rsum[2][4];
    #pragma unroll
    for (int mi = 0; mi < 2; ++mi)
        #pragma unroll
        for (int j = 0; j < 4; ++j) {
            float gm = gmaxs[mi * 16 + g * 4 + j];
            float s = 0.f;
            #pragma unroll
            for (int ni = 0; ni < 4; ++ni) s += expf(acc[mi][ni][j] - gm);
            rsum[mi][j] = s;
        }
    #pragma unroll
    for (int o = 1; o < 16; o <<= 1)
        #pragma unroll
        for (int mi = 0; mi < 2; ++mi)
            #pragma unroll
            for (int j = 0; j < 4; ++j)
                rsum[mi][j] += __shfl_xor(rsum[mi][j], o);
    if (r == 0) {
        #pragma unroll
        for (int mi = 0; mi < 2; ++mi)
            #pragma unroll
            for (int j = 0; j < 4; ++j)
                red[(mi * 16 + g * 4 + j) * 8 + wid] = rsum[mi][j];
    }
    __syncthreads();
    if (tid < 32) {
        float s = 0.f;
        #pragma unroll
        for (int w = 0; w < 8; ++w) s += red[tid * 8 + w];
        lses[tid] = gmaxs[tid] + logf(s);
    }
    __syncthreads();

    // ---- write output ----
    #pragma unroll
    for (int mi = 0; mi < 2; ++mi) {
        #pragma unroll
        for (int j = 0; j < 4; ++j) {
            float l = lses[mi * 16 + g * 4 + j];
            size_t rowoff = (size_t)(m0 + mi * 16 + g * 4 + j) * NC;
            #pragma unroll
            for (int ni = 0; ni < 4; ++ni)
                out[rowoff + wid * 64 + ni * 16 + r] = acc[mi][ni][j] - l;
        }
    }
}

// ---------------------------------------------------------------------------
extern "C" void kernel_launch(void* const* d_in, const int* in_sizes, int n_in,
                              void* d_out, int out_size, void* d_ws, size_t ws_size,
                              hipStream_t stream)
{
    const float* sup = (const float*)d_in[0];   // [2560,64,5,5]
    const float* qry = (const float*)d_in[1];   // [8192,64,5,5]
    const int*   lab = (const int*)d_in[2];     // [2560]
    float* out = (float*)d_out;                 // [8192,512]

    char* ws = (char*)d_ws;
    bf16_t* protos = (bf16_t*)ws;               // 512*1600*2 = 1,638,400 B
    float*  p2     = (float*)(ws + 1638400);    // 2 KB

    proto_kernel<<<NC, 256, 0, stream>>>(sup, lab, protos, p2);
    fused_kernel<<<NQ / 32, 512, 0, stream>>>(qry, protos, p2, out);
}